// Round 1
// baseline (1268.949 us; speedup 1.0000x reference)
//
#include <hip/hip_runtime.h>
#include <math.h>

#define N_NODES 50000
#define N_EDGES 800000
#define NGRAPH  1024
#define D       256
#define OUTD    128
#define NFEAT   9
#define VOCABSZ 100
#define NLAYERS 4
#define NEG_SLOPE 0.2f

// ---------------- CSR build ----------------
__global__ void set_deg_one(int* deg) {
    int v = blockIdx.x * blockDim.x + threadIdx.x;
    if (v < N_NODES) deg[v] = 1;   // self-loop
}

__global__ void hist_dst(const int* __restrict__ dst, int* __restrict__ deg) {
    int e = blockIdx.x * blockDim.x + threadIdx.x;
    if (e < N_EDGES) atomicAdd(&deg[dst[e]], 1);
}

__global__ __launch_bounds__(1024) void scan_rowptr(const int* __restrict__ deg, int* __restrict__ rowptr) {
    __shared__ int sums[1024];
    int tid = threadIdx.x;
    const int chunk = (N_NODES + 1023) / 1024;
    int b = tid * chunk;
    int e = b + chunk; if (e > N_NODES) e = N_NODES;
    int sum = 0;
    for (int i = b; i < e; ++i) sum += deg[i];
    sums[tid] = sum;
    __syncthreads();
    for (int off = 1; off < 1024; off <<= 1) {
        int v = (tid >= off) ? sums[tid - off] : 0;
        __syncthreads();
        sums[tid] += v;
        __syncthreads();
    }
    int running = (tid > 0) ? sums[tid - 1] : 0;
    for (int i = b; i < e; ++i) { rowptr[i] = running; running += deg[i]; }
    if (tid == 1023) rowptr[N_NODES] = running;
}

__global__ void init_cursor(const int* __restrict__ rowptr, int* __restrict__ cursor, int* __restrict__ ssrc) {
    int v = blockIdx.x * blockDim.x + threadIdx.x;
    if (v < N_NODES) {
        int p = rowptr[v];
        cursor[v] = p + 1;
        ssrc[p] = v;          // self-loop first
    }
}

__global__ void scatter_edges(const int* __restrict__ src, const int* __restrict__ dst,
                              int* __restrict__ cursor, int* __restrict__ ssrc) {
    int e = blockIdx.x * blockDim.x + threadIdx.x;
    if (e < N_EDGES) {
        int pos = atomicAdd(&cursor[dst[e]], 1);
        ssrc[pos] = src[e];
    }
}

// ---------------- Atom encoder ----------------
__global__ __launch_bounds__(256) void atom_encoder(const int* __restrict__ x,
                                                    const float* __restrict__ emb,
                                                    float* __restrict__ h) {
    int n = blockIdx.x;
    int d = threadIdx.x;
    __shared__ int xi[NFEAT];
    if (threadIdx.x < NFEAT) xi[threadIdx.x] = x[n * NFEAT + threadIdx.x];
    __syncthreads();
    float acc = 0.f;
    #pragma unroll
    for (int f = 0; f < NFEAT; ++f)
        acc += emb[(f * VOCABSZ + xi[f]) * D + d];
    h[n * D + d] = acc;
}

// ---------------- GEMM: C[N,256] = A[N,256] @ W[256,256] ----------------
#define BM 128
#define BN 64
#define BK 16
__global__ __launch_bounds__(256) void gemm_kernel(const float* __restrict__ A,
                                                   const float* __restrict__ W,
                                                   float* __restrict__ C) {
    __shared__ float a_s[BK][BM + 4];   // transposed: a_s[k][m]
    __shared__ float b_s[BK][BN + 4];
    int row0 = blockIdx.x * BM;
    int col0 = blockIdx.y * BN;
    int tid = threadIdx.x;
    int tr = tid >> 4;      // 0..15
    int tc = tid & 15;      // 0..15
    float acc[8][4];
    #pragma unroll
    for (int i = 0; i < 8; ++i)
        #pragma unroll
        for (int j = 0; j < 4; ++j) acc[i][j] = 0.f;

    for (int k0 = 0; k0 < D; k0 += BK) {
        #pragma unroll
        for (int q = 0; q < 2; ++q) {
            int idx = tid * 2 + q;        // 0..511
            int r = idx >> 2;             // 0..127
            int kq = idx & 3;             // 0..3
            int row = row0 + r; if (row >= N_NODES) row = N_NODES - 1;
            float4 v = *(const float4*)&A[row * D + k0 + kq * 4];
            a_s[kq * 4 + 0][r] = v.x;
            a_s[kq * 4 + 1][r] = v.y;
            a_s[kq * 4 + 2][r] = v.z;
            a_s[kq * 4 + 3][r] = v.w;
        }
        {
            int kk = tid >> 4;            // 0..15
            int nq = tid & 15;            // 0..15
            float4 v = *(const float4*)&W[(k0 + kk) * D + col0 + nq * 4];
            *(float4*)&b_s[kk][nq * 4] = v;
        }
        __syncthreads();
        #pragma unroll
        for (int k = 0; k < BK; ++k) {
            float4 a0 = *(const float4*)&a_s[k][tr * 8];
            float4 a1 = *(const float4*)&a_s[k][tr * 8 + 4];
            float4 bv4 = *(const float4*)&b_s[k][tc * 4];
            float av[8] = {a0.x, a0.y, a0.z, a0.w, a1.x, a1.y, a1.z, a1.w};
            float bv[4] = {bv4.x, bv4.y, bv4.z, bv4.w};
            #pragma unroll
            for (int i = 0; i < 8; ++i)
                #pragma unroll
                for (int j = 0; j < 4; ++j)
                    acc[i][j] += av[i] * bv[j];
        }
        __syncthreads();
    }
    #pragma unroll
    for (int i = 0; i < 8; ++i) {
        int row = row0 + tr * 8 + i;
        if (row < N_NODES) {
            float4 o = make_float4(acc[i][0], acc[i][1], acc[i][2], acc[i][3]);
            *(float4*)&C[row * D + col0 + tc * 4] = o;
        }
    }
}

// ---------------- per-node attention scores s,t ----------------
__global__ __launch_bounds__(256) void st_kernel(const float* __restrict__ hW,
                                                 const float* __restrict__ asrc,
                                                 const float* __restrict__ adst,
                                                 float* __restrict__ s, float* __restrict__ t) {
    int wave = (blockIdx.x * blockDim.x + threadIdx.x) >> 6;
    int lane = threadIdx.x & 63;
    if (wave >= N_NODES) return;
    float4 h = ((const float4*)hW)[wave * 64 + lane];
    float4 a = ((const float4*)asrc)[lane];
    float4 b = ((const float4*)adst)[lane];
    float ps = h.x * a.x + h.y * a.y + h.z * a.z + h.w * a.w;
    float pt = h.x * b.x + h.y * b.y + h.z * b.z + h.w * b.w;
    #pragma unroll
    for (int off = 32; off; off >>= 1) {
        ps += __shfl_down(ps, off, 64);
        pt += __shfl_down(pt, off, 64);
    }
    if (lane == 0) { s[wave] = ps; t[wave] = pt; }
}

// ---------------- attention + aggregate (wave per dst) ----------------
__global__ __launch_bounds__(256) void aggregate_kernel(const float* __restrict__ hW,
                                                        const float* __restrict__ s,
                                                        const float* __restrict__ t,
                                                        const int* __restrict__ rowptr,
                                                        const int* __restrict__ ssrc,
                                                        const float* __restrict__ bias,
                                                        float* __restrict__ hout) {
    int v = (blockIdx.x * blockDim.x + threadIdx.x) >> 6;
    int lane = threadIdx.x & 63;
    if (v >= N_NODES) return;
    int beg = rowptr[v], end = rowptr[v + 1];
    float tv = t[v];
    float m = -1e30f;
    for (int i = beg; i < end; ++i) {
        float e = s[ssrc[i]] + tv;
        e = (e > 0.f) ? e : NEG_SLOPE * e;
        m = fmaxf(m, e);
    }
    float4 acc = make_float4(0.f, 0.f, 0.f, 0.f);
    float denom = 0.f;
    for (int i = beg; i < end; ++i) {
        int u = ssrc[i];
        float e = s[u] + tv;
        e = (e > 0.f) ? e : NEG_SLOPE * e;
        float p = __expf(e - m);
        denom += p;
        float4 hv = ((const float4*)hW)[u * 64 + lane];
        acc.x += p * hv.x; acc.y += p * hv.y; acc.z += p * hv.z; acc.w += p * hv.w;
    }
    float inv = 1.f / denom;
    float4 bb = ((const float4*)bias)[lane];
    float4 o;
    o.x = fmaxf(acc.x * inv + bb.x, 0.f);
    o.y = fmaxf(acc.y * inv + bb.y, 0.f);
    o.z = fmaxf(acc.z * inv + bb.z, 0.f);
    o.w = fmaxf(acc.w * inv + bb.w, 0.f);
    ((float4*)hout)[v * 64 + lane] = o;
}

// ---------------- pooling ----------------
__global__ void growptr_kernel(const int* __restrict__ batch, int* __restrict__ growptr) {
    int n = blockIdx.x * blockDim.x + threadIdx.x;
    if (n >= N_NODES) return;
    int b = batch[n];
    int prev = (n == 0) ? -1 : batch[n - 1];
    for (int g = prev + 1; g <= b; ++g) growptr[g] = n;
    if (n == N_NODES - 1) {
        for (int g = b + 1; g <= NGRAPH; ++g) growptr[g] = N_NODES;
    }
}

__global__ __launch_bounds__(256) void pool_kernel(const float* __restrict__ h,
                                                   const int* __restrict__ growptr,
                                                   float* __restrict__ feats) {
    int g = (blockIdx.x * blockDim.x + threadIdx.x) >> 6;
    int lane = threadIdx.x & 63;
    if (g >= NGRAPH) return;
    int beg = growptr[g], end = growptr[g + 1];
    float4 add = make_float4(0.f, 0.f, 0.f, 0.f);
    float4 mx = make_float4(-1e30f, -1e30f, -1e30f, -1e30f);
    for (int v = beg; v < end; ++v) {
        float4 hv = ((const float4*)h)[v * 64 + lane];
        add.x += hv.x; add.y += hv.y; add.z += hv.z; add.w += hv.w;
        mx.x = fmaxf(mx.x, hv.x); mx.y = fmaxf(mx.y, hv.y);
        mx.z = fmaxf(mx.z, hv.z); mx.w = fmaxf(mx.w, hv.w);
    }
    float cnt = (float)(end - beg);
    float invc = 1.f / fmaxf(cnt, 1.f);
    if (cnt <= 0.f) { mx = make_float4(0.f, 0.f, 0.f, 0.f); }
    float4 mean = make_float4(add.x * invc, add.y * invc, add.z * invc, add.w * invc);
    float* fr = feats + (size_t)g * 3 * D;
    *(float4*)&fr[0 * D + 4 * lane] = mean;
    *(float4*)&fr[1 * D + 4 * lane] = add;
    *(float4*)&fr[2 * D + 4 * lane] = mx;
}

// ---------------- final linear ----------------
__global__ __launch_bounds__(128) void final_linear(const float* __restrict__ feats,
                                                    const float* __restrict__ lw,
                                                    const float* __restrict__ lb,
                                                    float* __restrict__ out) {
    int g = blockIdx.x;
    int j = threadIdx.x;   // 0..127
    __shared__ float f[3 * D];
    for (int i = j; i < 3 * D; i += OUTD) f[i] = feats[(size_t)g * 3 * D + i];
    __syncthreads();
    float acc = lb[j];
    #pragma unroll 8
    for (int k = 0; k < 3 * D; ++k)
        acc += f[k] * lw[k * OUTD + j];
    out[g * OUTD + j] = acc;
}

extern "C" void kernel_launch(void* const* d_in, const int* in_sizes, int n_in,
                              void* d_out, int out_size, void* d_ws, size_t ws_size,
                              hipStream_t stream) {
    const int*   x        = (const int*)d_in[0];
    const int*   edge_idx = (const int*)d_in[1];
    const int*   batch    = (const int*)d_in[2];
    const float* atom_emb = (const float*)d_in[3];
    const float* Ws       = (const float*)d_in[4];
    const float* a_src    = (const float*)d_in[5];
    const float* a_dst    = (const float*)d_in[6];
    const float* biases   = (const float*)d_in[7];
    const float* lin_w    = (const float*)d_in[8];
    const float* lin_b    = (const float*)d_in[9];
    float* out = (float*)d_out;

    char* ws = (char*)d_ws;
    size_t off = 0;
    auto alloc = [&](size_t bytes) -> void* {
        void* p = ws + off;
        off += (bytes + 255) & ~(size_t)255;
        return p;
    };
    float* bufA   = (float*)alloc(sizeof(float) * (size_t)N_NODES * D);
    float* bufB   = (float*)alloc(sizeof(float) * (size_t)N_NODES * D);
    float* s      = (float*)alloc(sizeof(float) * N_NODES);
    float* t      = (float*)alloc(sizeof(float) * N_NODES);
    int*   deg    = (int*)alloc(sizeof(int) * N_NODES);       // reused as cursor
    int*   rowptr = (int*)alloc(sizeof(int) * (N_NODES + 1));
    int*   ssrc   = (int*)alloc(sizeof(int) * (N_EDGES + N_NODES));
    int*   growp  = (int*)alloc(sizeof(int) * (NGRAPH + 1));
    float* feats  = (float*)alloc(sizeof(float) * (size_t)NGRAPH * 3 * D);

    const int* esrc = edge_idx;
    const int* edst = edge_idx + N_EDGES;

    set_deg_one<<<(N_NODES + 255) / 256, 256, 0, stream>>>(deg);
    hist_dst<<<(N_EDGES + 255) / 256, 256, 0, stream>>>(edst, deg);
    scan_rowptr<<<1, 1024, 0, stream>>>(deg, rowptr);
    init_cursor<<<(N_NODES + 255) / 256, 256, 0, stream>>>(rowptr, deg, ssrc);
    scatter_edges<<<(N_EDGES + 255) / 256, 256, 0, stream>>>(esrc, edst, deg, ssrc);

    atom_encoder<<<N_NODES, 256, 0, stream>>>(x, atom_emb, bufA);

    for (int l = 0; l < NLAYERS; ++l) {
        dim3 ggrid((N_NODES + BM - 1) / BM, D / BN);
        gemm_kernel<<<ggrid, 256, 0, stream>>>(bufA, Ws + (size_t)l * D * D, bufB);
        st_kernel<<<(N_NODES + 3) / 4, 256, 0, stream>>>(bufB, a_src + l * D, a_dst + l * D, s, t);
        aggregate_kernel<<<(N_NODES + 3) / 4, 256, 0, stream>>>(bufB, s, t, rowptr, ssrc,
                                                                biases + l * D, bufA);
    }

    growptr_kernel<<<(N_NODES + 255) / 256, 256, 0, stream>>>(batch, growp);
    pool_kernel<<<(NGRAPH + 3) / 4, 256, 0, stream>>>(bufA, growp, feats);
    final_linear<<<NGRAPH, OUTD, 0, stream>>>(feats, lin_w, lin_b, out);
}

// Round 2
// 916.344 us; speedup vs baseline: 1.3848x; 1.3848x over previous
//
#include <hip/hip_runtime.h>
#include <math.h>

#define N_NODES 50000
#define N_EDGES 800000
#define NGRAPH  1024
#define D       256
#define OUTD    128
#define NFEAT   9
#define VOCABSZ 100
#define NLAYERS 4
#define NEG_SLOPE 0.2f

typedef __attribute__((ext_vector_type(8))) short short8;   // 8 bf16 (4 VGPRs)
typedef __attribute__((ext_vector_type(4))) float f32x4;

static __device__ __forceinline__ unsigned short f2bf(float f) {
    unsigned int u = __float_as_uint(f);
    u = (u + 0x7FFFu + ((u >> 16) & 1u)) >> 16;
    return (unsigned short)u;
}
static __device__ __forceinline__ float bf2f(unsigned short u) {
    return __uint_as_float(((unsigned int)u) << 16);
}

// ---------------- CSR build ----------------
__global__ void set_deg_one(int* deg) {
    int v = blockIdx.x * blockDim.x + threadIdx.x;
    if (v < N_NODES) deg[v] = 1;   // self-loop
}

__global__ void hist_dst(const int* __restrict__ dst, int* __restrict__ deg) {
    int e = blockIdx.x * blockDim.x + threadIdx.x;
    if (e < N_EDGES) atomicAdd(&deg[dst[e]], 1);
}

__global__ __launch_bounds__(1024) void scan_rowptr(const int* __restrict__ deg, int* __restrict__ rowptr) {
    __shared__ int sums[1024];
    int tid = threadIdx.x;
    const int chunk = (N_NODES + 1023) / 1024;
    int b = tid * chunk;
    int e = b + chunk; if (e > N_NODES) e = N_NODES;
    int sum = 0;
    for (int i = b; i < e; ++i) sum += deg[i];
    sums[tid] = sum;
    __syncthreads();
    for (int off = 1; off < 1024; off <<= 1) {
        int v = (tid >= off) ? sums[tid - off] : 0;
        __syncthreads();
        sums[tid] += v;
        __syncthreads();
    }
    int running = (tid > 0) ? sums[tid - 1] : 0;
    for (int i = b; i < e; ++i) { rowptr[i] = running; running += deg[i]; }
    if (tid == 1023) rowptr[N_NODES] = running;
}

__global__ void init_cursor(const int* __restrict__ rowptr, int* __restrict__ cursor, int* __restrict__ ssrc) {
    int v = blockIdx.x * blockDim.x + threadIdx.x;
    if (v < N_NODES) {
        int p = rowptr[v];
        cursor[v] = p + 1;
        ssrc[p] = v;          // self-loop first
    }
}

__global__ void scatter_edges(const int* __restrict__ src, const int* __restrict__ dst,
                              int* __restrict__ cursor, int* __restrict__ ssrc) {
    int e = blockIdx.x * blockDim.x + threadIdx.x;
    if (e < N_EDGES) {
        int pos = atomicAdd(&cursor[dst[e]], 1);
        ssrc[pos] = src[e];
    }
}

// ---------------- W transpose + bf16 convert: Wt[l][n][k] = W[l][k][n] ----------------
__global__ __launch_bounds__(256) void wt_kernel(const float* __restrict__ W, unsigned short* __restrict__ Wt) {
    int t = blockIdx.x * 256 + threadIdx.x;           // over l*65536 + k*256 + n
    int l = t >> 16;
    int k = (t >> 8) & 255;
    int n = t & 255;
    float v = W[t];
    Wt[(l << 16) + n * 256 + k] = f2bf(v);
}

// ---------------- Atom encoder (bf16 out) ----------------
__global__ __launch_bounds__(256) void atom_encoder(const int* __restrict__ x,
                                                    const float* __restrict__ emb,
                                                    unsigned short* __restrict__ h) {
    int node = blockIdx.x * 4 + (threadIdx.x >> 6);
    int lane = threadIdx.x & 63;
    if (node >= N_NODES) return;
    float4 acc = make_float4(0.f, 0.f, 0.f, 0.f);
    #pragma unroll
    for (int f = 0; f < NFEAT; ++f) {
        int xi = x[node * NFEAT + f];
        float4 v = *(const float4*)&emb[(size_t)(f * VOCABSZ + xi) * D + lane * 4];
        acc.x += v.x; acc.y += v.y; acc.z += v.z; acc.w += v.w;
    }
    ushort4 o;
    o.x = f2bf(acc.x); o.y = f2bf(acc.y); o.z = f2bf(acc.z); o.w = f2bf(acc.w);
    *(ushort4*)&h[node * D + lane * 4] = o;
}

// ---------------- bf16 MFMA GEMM: C[N,256] = A[N,256] @ W[256,256] ----------------
// A bf16 row-major; Wt bf16 [n][k]; C bf16 row-major.
#define GBM 128
#define GBN 128
#define GBK 64
__global__ __launch_bounds__(256) void gemm_bf16(const unsigned short* __restrict__ A,
                                                 const unsigned short* __restrict__ Wt,
                                                 unsigned short* __restrict__ C) {
    __shared__ unsigned short a_s[GBM * GBK];
    __shared__ unsigned short b_s[GBN * GBK];
    int row0 = blockIdx.x * GBM;
    int col0 = blockIdx.y * GBN;
    int tid = threadIdx.x;
    int wid = tid >> 6;
    int lane = tid & 63;
    int wm = wid >> 1, wn = wid & 1;     // 2x2 wave grid, each wave 64x64
    int l15 = lane & 15;
    int lhi = lane >> 4;                 // 0..3

    f32x4 acc[4][4];
    #pragma unroll
    for (int i = 0; i < 4; ++i)
        #pragma unroll
        for (int j = 0; j < 4; ++j) acc[i][j] = (f32x4){0.f, 0.f, 0.f, 0.f};

    for (int k0 = 0; k0 < D; k0 += GBK) {
        // stage A tile [128 rows][64 k], XOR-swizzled in 16B chunks
        #pragma unroll
        for (int p = 0; p < 4; ++p) {
            int idx = p * 256 + tid;
            int r = idx >> 3;
            int c = idx & 7;
            int grow = row0 + r; if (grow >= N_NODES) grow = N_NODES - 1;
            int4 v = *(const int4*)&A[(size_t)grow * D + k0 + c * 8];
            *(int4*)&a_s[r * GBK + ((c ^ (r & 7)) << 3)] = v;
        }
        // stage B tile: rows n = col0..col0+127, k = k0..k0+63 from Wt [n][k]
        #pragma unroll
        for (int p = 0; p < 4; ++p) {
            int idx = p * 256 + tid;
            int r = idx >> 3;
            int c = idx & 7;
            int4 v = *(const int4*)&Wt[(size_t)(col0 + r) * D + k0 + c * 8];
            *(int4*)&b_s[r * GBK + ((c ^ (r & 7)) << 3)] = v;
        }
        __syncthreads();
        #pragma unroll
        for (int ks = 0; ks < 2; ++ks) {
            short8 af[4], bf[4];
            #pragma unroll
            for (int m = 0; m < 4; ++m) {
                int r = wm * 64 + m * 16 + l15;
                int c = ks * 4 + lhi;
                af[m] = *(const short8*)&a_s[r * GBK + ((c ^ (r & 7)) << 3)];
            }
            #pragma unroll
            for (int n = 0; n < 4; ++n) {
                int r = wn * 64 + n * 16 + l15;
                int c = ks * 4 + lhi;
                bf[n] = *(const short8*)&b_s[r * GBK + ((c ^ (r & 7)) << 3)];
            }
            #pragma unroll
            for (int m = 0; m < 4; ++m)
                #pragma unroll
                for (int n = 0; n < 4; ++n)
                    acc[m][n] = __builtin_amdgcn_mfma_f32_16x16x32_bf16(af[m], bf[n], acc[m][n], 0, 0, 0);
        }
        __syncthreads();
    }
    // epilogue: C[row][col] bf16; C/D layout: col=lane&15, row=(lane>>4)*4+reg
    #pragma unroll
    for (int m = 0; m < 4; ++m) {
        #pragma unroll
        for (int r = 0; r < 4; ++r) {
            int grow = row0 + wm * 64 + m * 16 + lhi * 4 + r;
            if (grow < N_NODES) {
                #pragma unroll
                for (int n = 0; n < 4; ++n) {
                    int gcol = col0 + wn * 64 + n * 16 + l15;
                    C[(size_t)grow * D + gcol] = f2bf(acc[m][n][r]);
                }
            }
        }
    }
}

// ---------------- per-node attention scores s,t (bf16 input) ----------------
__global__ __launch_bounds__(256) void st_kernel(const unsigned short* __restrict__ hW,
                                                 const float* __restrict__ asrc,
                                                 const float* __restrict__ adst,
                                                 float* __restrict__ s, float* __restrict__ t) {
    int node = blockIdx.x * 4 + (threadIdx.x >> 6);
    int lane = threadIdx.x & 63;
    if (node >= N_NODES) return;
    ushort4 hv = *(const ushort4*)&hW[(size_t)node * D + lane * 4];
    float4 a = *(const float4*)&asrc[lane * 4];
    float4 b = *(const float4*)&adst[lane * 4];
    float h0 = bf2f(hv.x), h1 = bf2f(hv.y), h2 = bf2f(hv.z), h3 = bf2f(hv.w);
    float ps = h0 * a.x + h1 * a.y + h2 * a.z + h3 * a.w;
    float pt = h0 * b.x + h1 * b.y + h2 * b.z + h3 * b.w;
    #pragma unroll
    for (int off = 32; off; off >>= 1) {
        ps += __shfl_down(ps, off, 64);
        pt += __shfl_down(pt, off, 64);
    }
    if (lane == 0) { s[node] = ps; t[node] = pt; }
}

// ---------------- attention + aggregate (wave per dst, bf16 gather) ----------------
__global__ __launch_bounds__(256) void aggregate_kernel(const unsigned short* __restrict__ hW,
                                                        const float* __restrict__ s,
                                                        const float* __restrict__ t,
                                                        const int* __restrict__ rowptr,
                                                        const int* __restrict__ ssrc,
                                                        const float* __restrict__ bias,
                                                        unsigned short* __restrict__ hout) {
    int v = (blockIdx.x * blockDim.x + threadIdx.x) >> 6;
    int lane = threadIdx.x & 63;
    if (v >= N_NODES) return;
    int beg = rowptr[v], end = rowptr[v + 1];
    float tv = t[v];
    float m = -1e30f;
    for (int i = beg; i < end; ++i) {
        float e = s[ssrc[i]] + tv;
        e = (e > 0.f) ? e : NEG_SLOPE * e;
        m = fmaxf(m, e);
    }
    float4 acc = make_float4(0.f, 0.f, 0.f, 0.f);
    float denom = 0.f;
    for (int i = beg; i < end; ++i) {
        int u = ssrc[i];
        float e = s[u] + tv;
        e = (e > 0.f) ? e : NEG_SLOPE * e;
        float p = __expf(e - m);
        denom += p;
        ushort4 hv = *(const ushort4*)&hW[(size_t)u * D + lane * 4];
        acc.x += p * bf2f(hv.x); acc.y += p * bf2f(hv.y);
        acc.z += p * bf2f(hv.z); acc.w += p * bf2f(hv.w);
    }
    float inv = 1.f / denom;
    float4 bb = *(const float4*)&bias[lane * 4];
    ushort4 o;
    o.x = f2bf(fmaxf(acc.x * inv + bb.x, 0.f));
    o.y = f2bf(fmaxf(acc.y * inv + bb.y, 0.f));
    o.z = f2bf(fmaxf(acc.z * inv + bb.z, 0.f));
    o.w = f2bf(fmaxf(acc.w * inv + bb.w, 0.f));
    *(ushort4*)&hout[(size_t)v * D + lane * 4] = o;
}

// ---------------- pooling ----------------
__global__ void growptr_kernel(const int* __restrict__ batch, int* __restrict__ growptr) {
    int n = blockIdx.x * blockDim.x + threadIdx.x;
    if (n >= N_NODES) return;
    int b = batch[n];
    int prev = (n == 0) ? -1 : batch[n - 1];
    for (int g = prev + 1; g <= b; ++g) growptr[g] = n;
    if (n == N_NODES - 1) {
        for (int g = b + 1; g <= NGRAPH; ++g) growptr[g] = N_NODES;
    }
}

__global__ __launch_bounds__(256) void pool_kernel(const unsigned short* __restrict__ h,
                                                   const int* __restrict__ growptr,
                                                   float* __restrict__ feats) {
    int g = (blockIdx.x * blockDim.x + threadIdx.x) >> 6;
    int lane = threadIdx.x & 63;
    if (g >= NGRAPH) return;
    int beg = growptr[g], end = growptr[g + 1];
    float4 add = make_float4(0.f, 0.f, 0.f, 0.f);
    float4 mx = make_float4(-1e30f, -1e30f, -1e30f, -1e30f);
    for (int v = beg; v < end; ++v) {
        ushort4 hv = *(const ushort4*)&h[(size_t)v * D + lane * 4];
        float h0 = bf2f(hv.x), h1 = bf2f(hv.y), h2 = bf2f(hv.z), h3 = bf2f(hv.w);
        add.x += h0; add.y += h1; add.z += h2; add.w += h3;
        mx.x = fmaxf(mx.x, h0); mx.y = fmaxf(mx.y, h1);
        mx.z = fmaxf(mx.z, h2); mx.w = fmaxf(mx.w, h3);
    }
    float cnt = (float)(end - beg);
    float invc = 1.f / fmaxf(cnt, 1.f);
    if (cnt <= 0.f) { mx = make_float4(0.f, 0.f, 0.f, 0.f); }
    float4 mean = make_float4(add.x * invc, add.y * invc, add.z * invc, add.w * invc);
    float* fr = feats + (size_t)g * 3 * D;
    *(float4*)&fr[0 * D + 4 * lane] = mean;
    *(float4*)&fr[1 * D + 4 * lane] = add;
    *(float4*)&fr[2 * D + 4 * lane] = mx;
}

// ---------------- final linear ----------------
__global__ __launch_bounds__(128) void final_linear(const float* __restrict__ feats,
                                                    const float* __restrict__ lw,
                                                    const float* __restrict__ lb,
                                                    float* __restrict__ out) {
    int g = blockIdx.x;
    int j = threadIdx.x;   // 0..127
    __shared__ float f[3 * D];
    for (int i = j; i < 3 * D; i += OUTD) f[i] = feats[(size_t)g * 3 * D + i];
    __syncthreads();
    float acc = lb[j];
    #pragma unroll 8
    for (int k = 0; k < 3 * D; ++k)
        acc += f[k] * lw[k * OUTD + j];
    out[g * OUTD + j] = acc;
}

extern "C" void kernel_launch(void* const* d_in, const int* in_sizes, int n_in,
                              void* d_out, int out_size, void* d_ws, size_t ws_size,
                              hipStream_t stream) {
    const int*   x        = (const int*)d_in[0];
    const int*   edge_idx = (const int*)d_in[1];
    const int*   batch    = (const int*)d_in[2];
    const float* atom_emb = (const float*)d_in[3];
    const float* Ws       = (const float*)d_in[4];
    const float* a_src    = (const float*)d_in[5];
    const float* a_dst    = (const float*)d_in[6];
    const float* biases   = (const float*)d_in[7];
    const float* lin_w    = (const float*)d_in[8];
    const float* lin_b    = (const float*)d_in[9];
    float* out = (float*)d_out;

    char* ws = (char*)d_ws;
    size_t off = 0;
    auto alloc = [&](size_t bytes) -> void* {
        void* p = ws + off;
        off += (bytes + 255) & ~(size_t)255;
        return p;
    };
    unsigned short* bufA = (unsigned short*)alloc(sizeof(short) * (size_t)N_NODES * D);
    unsigned short* bufB = (unsigned short*)alloc(sizeof(short) * (size_t)N_NODES * D);
    unsigned short* Wt   = (unsigned short*)alloc(sizeof(short) * NLAYERS * D * D);
    float* s      = (float*)alloc(sizeof(float) * N_NODES);
    float* t      = (float*)alloc(sizeof(float) * N_NODES);
    int*   deg    = (int*)alloc(sizeof(int) * N_NODES);       // reused as cursor
    int*   rowptr = (int*)alloc(sizeof(int) * (N_NODES + 1));
    int*   ssrc   = (int*)alloc(sizeof(int) * (N_EDGES + N_NODES));
    int*   growp  = (int*)alloc(sizeof(int) * (NGRAPH + 1));
    float* feats  = (float*)alloc(sizeof(float) * (size_t)NGRAPH * 3 * D);

    const int* esrc = edge_idx;
    const int* edst = edge_idx + N_EDGES;

    set_deg_one<<<(N_NODES + 255) / 256, 256, 0, stream>>>(deg);
    hist_dst<<<(N_EDGES + 255) / 256, 256, 0, stream>>>(edst, deg);
    scan_rowptr<<<1, 1024, 0, stream>>>(deg, rowptr);
    init_cursor<<<(N_NODES + 255) / 256, 256, 0, stream>>>(rowptr, deg, ssrc);
    scatter_edges<<<(N_EDGES + 255) / 256, 256, 0, stream>>>(esrc, edst, deg, ssrc);

    wt_kernel<<<NLAYERS * D * D / 256, 256, 0, stream>>>(Ws, Wt);
    atom_encoder<<<(N_NODES + 3) / 4, 256, 0, stream>>>(x, atom_emb, bufA);

    for (int l = 0; l < NLAYERS; ++l) {
        dim3 ggrid((N_NODES + GBM - 1) / GBM, D / GBN);
        gemm_bf16<<<ggrid, 256, 0, stream>>>(bufA, Wt + (size_t)l * D * D, bufB);
        st_kernel<<<(N_NODES + 3) / 4, 256, 0, stream>>>(bufB, a_src + l * D, a_dst + l * D, s, t);
        aggregate_kernel<<<(N_NODES + 3) / 4, 256, 0, stream>>>(bufB, s, t, rowptr, ssrc,
                                                                biases + l * D, bufA);
    }

    growptr_kernel<<<(N_NODES + 255) / 256, 256, 0, stream>>>(batch, growp);
    pool_kernel<<<(NGRAPH + 3) / 4, 256, 0, stream>>>(bufA, growp, feats);
    final_linear<<<NGRAPH, OUTD, 0, stream>>>(feats, lin_w, lin_b, out);
}

// Round 3
// 615.182 us; speedup vs baseline: 2.0627x; 1.4896x over previous
//
#include <hip/hip_runtime.h>
#include <math.h>

#define N_NODES 50000
#define N_EDGES 800000
#define NGRAPH  1024
#define D       256
#define OUTD    128
#define NFEAT   9
#define VOCABSZ 100
#define NLAYERS 4
#define NEG_SLOPE 0.2f

typedef __attribute__((ext_vector_type(8))) short short8;   // 8 bf16 (4 VGPRs)
typedef __attribute__((ext_vector_type(4))) float f32x4;

static __device__ __forceinline__ unsigned short f2bf(float f) {
    unsigned int u = __float_as_uint(f);
    u = (u + 0x7FFFu + ((u >> 16) & 1u)) >> 16;
    return (unsigned short)u;
}
static __device__ __forceinline__ float bf2f(unsigned short u) {
    return __uint_as_float(((unsigned int)u) << 16);
}

#define GLOAD_LDS16(g, l) __builtin_amdgcn_global_load_lds( \
    (const __attribute__((address_space(1))) void*)(g), \
    (__attribute__((address_space(3))) void*)(l), 16, 0, 0)

// ---------------- CSR build ----------------
__global__ void set_deg_one(int* deg) {
    int v = blockIdx.x * blockDim.x + threadIdx.x;
    if (v < N_NODES) deg[v] = 1;   // self-loop
}

__global__ void hist_dst(const int* __restrict__ dst, int* __restrict__ deg) {
    int e = blockIdx.x * blockDim.x + threadIdx.x;
    if (e < N_EDGES) atomicAdd(&deg[dst[e]], 1);
}

__global__ __launch_bounds__(1024) void scan_rowptr(const int* __restrict__ deg, int* __restrict__ rowptr) {
    __shared__ int sums[1024];
    int tid = threadIdx.x;
    const int chunk = (N_NODES + 1023) / 1024;
    int b = tid * chunk;
    int e = b + chunk; if (e > N_NODES) e = N_NODES;
    int sum = 0;
    for (int i = b; i < e; ++i) sum += deg[i];
    sums[tid] = sum;
    __syncthreads();
    for (int off = 1; off < 1024; off <<= 1) {
        int v = (tid >= off) ? sums[tid - off] : 0;
        __syncthreads();
        sums[tid] += v;
        __syncthreads();
    }
    int running = (tid > 0) ? sums[tid - 1] : 0;
    for (int i = b; i < e; ++i) { rowptr[i] = running; running += deg[i]; }
    if (tid == 1023) rowptr[N_NODES] = running;
}

__global__ void init_cursor(const int* __restrict__ rowptr, int* __restrict__ cursor, int* __restrict__ ssrc) {
    int v = blockIdx.x * blockDim.x + threadIdx.x;
    if (v < N_NODES) {
        int p = rowptr[v];
        cursor[v] = p + 1;
        ssrc[p] = v;          // self-loop first
    }
}

__global__ void scatter_edges(const int* __restrict__ src, const int* __restrict__ dst,
                              int* __restrict__ cursor, int* __restrict__ ssrc) {
    int e = blockIdx.x * blockDim.x + threadIdx.x;
    if (e < N_EDGES) {
        int pos = atomicAdd(&cursor[dst[e]], 1);
        ssrc[pos] = src[e];
    }
}

// ---------------- W transpose + bf16 convert: Wt[l][n][k] = W[l][k][n] ----------------
__global__ __launch_bounds__(256) void wt_kernel(const float* __restrict__ W, unsigned short* __restrict__ Wt) {
    int t = blockIdx.x * 256 + threadIdx.x;           // over l*65536 + k*256 + n
    int l = t >> 16;
    int k = (t >> 8) & 255;
    int n = t & 255;
    float v = W[t];
    Wt[(l << 16) + n * 256 + k] = f2bf(v);
}

__global__ void zero_st(float* __restrict__ s, float* __restrict__ t) {
    int i = blockIdx.x * blockDim.x + threadIdx.x;
    if (i < N_NODES) { s[i] = 0.f; t[i] = 0.f; }
}

// ---------------- Atom encoder (bf16 out) ----------------
__global__ __launch_bounds__(256) void atom_encoder(const int* __restrict__ x,
                                                    const float* __restrict__ emb,
                                                    unsigned short* __restrict__ h) {
    int node = blockIdx.x * 4 + (threadIdx.x >> 6);
    int lane = threadIdx.x & 63;
    if (node >= N_NODES) return;
    float4 acc = make_float4(0.f, 0.f, 0.f, 0.f);
    #pragma unroll
    for (int f = 0; f < NFEAT; ++f) {
        int xi = x[node * NFEAT + f];
        float4 v = *(const float4*)&emb[(size_t)(f * VOCABSZ + xi) * D + lane * 4];
        acc.x += v.x; acc.y += v.y; acc.z += v.z; acc.w += v.w;
    }
    ushort4 o;
    o.x = f2bf(acc.x); o.y = f2bf(acc.y); o.z = f2bf(acc.z); o.w = f2bf(acc.w);
    *(ushort4*)&h[node * D + lane * 4] = o;
}

// ---------------- bf16 MFMA GEMM + fused s/t epilogue ----------------
// C[N,256] = A[N,256] @ W ;  s[row] += sum_col C*asrc (fp32), t likewise.
#define GBM 128
#define GBN 128
#define GBK 64
__global__ __launch_bounds__(256) void gemm_bf16(const unsigned short* __restrict__ A,
                                                 const unsigned short* __restrict__ Wt,
                                                 const float* __restrict__ asrc,
                                                 const float* __restrict__ adst,
                                                 unsigned short* __restrict__ C,
                                                 float* __restrict__ s_out,
                                                 float* __restrict__ t_out) {
    __shared__ unsigned short a_s[2][GBM * GBK];
    __shared__ unsigned short b_s[2][GBM * GBK];
    int row0 = blockIdx.x * GBM;
    int col0 = blockIdx.y * GBN;
    int tid = threadIdx.x;
    int wid = tid >> 6;
    int lane = tid & 63;
    int wm = wid >> 1, wn = wid & 1;     // 2x2 wave grid, each wave 64x64
    int l15 = lane & 15;
    int lhi = lane >> 4;                 // 0..3

    // per-lane swizzled-source offsets for the 4 staging instructions of this wave
    int srcA[4], srcB[4];
    #pragma unroll
    for (int q = 0; q < 4; ++q) {
        int slot = (wid * 4 + q) * 64 + lane;   // 0..1023
        int r = slot >> 3, c = slot & 7;
        int ra = row0 + r; if (ra > N_NODES - 1) ra = N_NODES - 1;
        srcA[q] = ra * D + ((c ^ (r & 7)) << 3);
        srcB[q] = (col0 + r) * D + ((c ^ (r & 7)) << 3);
    }

    f32x4 acc[4][4];
    #pragma unroll
    for (int i = 0; i < 4; ++i)
        #pragma unroll
        for (int j = 0; j < 4; ++j) acc[i][j] = (f32x4){0.f, 0.f, 0.f, 0.f};

    // prologue stage
    #pragma unroll
    for (int q = 0; q < 4; ++q) {
        GLOAD_LDS16(A + srcA[q], &a_s[0][(wid * 4 + q) * 512]);
        GLOAD_LDS16(Wt + srcB[q], &b_s[0][(wid * 4 + q) * 512]);
    }
    __syncthreads();

    #pragma unroll
    for (int step = 0; step < 4; ++step) {
        int cur = step & 1;
        if (step < 3) {
            int k0 = (step + 1) * GBK;
            #pragma unroll
            for (int q = 0; q < 4; ++q) {
                GLOAD_LDS16(A + srcA[q] + k0, &a_s[cur ^ 1][(wid * 4 + q) * 512]);
                GLOAD_LDS16(Wt + srcB[q] + k0, &b_s[cur ^ 1][(wid * 4 + q) * 512]);
            }
        }
        #pragma unroll
        for (int ks = 0; ks < 2; ++ks) {
            short8 af[4], bf[4];
            #pragma unroll
            for (int m = 0; m < 4; ++m) {
                int r = wm * 64 + m * 16 + l15;
                int c = ks * 4 + lhi;
                af[m] = *(const short8*)&a_s[cur][r * GBK + ((c ^ (r & 7)) << 3)];
            }
            #pragma unroll
            for (int n = 0; n < 4; ++n) {
                int r = wn * 64 + n * 16 + l15;
                int c = ks * 4 + lhi;
                bf[n] = *(const short8*)&b_s[cur][r * GBK + ((c ^ (r & 7)) << 3)];
            }
            #pragma unroll
            for (int m = 0; m < 4; ++m)
                #pragma unroll
                for (int n = 0; n < 4; ++n)
                    acc[m][n] = __builtin_amdgcn_mfma_f32_16x16x32_bf16(af[m], bf[n], acc[m][n], 0, 0, 0);
        }
        __syncthreads();
    }

    // epilogue 1: C bf16 store. C/D layout: col=lane&15, row=(lane>>4)*4+reg
    #pragma unroll
    for (int m = 0; m < 4; ++m) {
        #pragma unroll
        for (int r = 0; r < 4; ++r) {
            int grow = row0 + wm * 64 + m * 16 + lhi * 4 + r;
            if (grow < N_NODES) {
                #pragma unroll
                for (int n = 0; n < 4; ++n) {
                    int gcol = col0 + wn * 64 + n * 16 + l15;
                    C[(size_t)grow * D + gcol] = f2bf(acc[m][n][r]);
                }
            }
        }
    }

    // epilogue 2: fused partial s,t (fp32) per row over this block's 128 cols
    float av[4], bv[4];
    #pragma unroll
    for (int n = 0; n < 4; ++n) {
        int gcol = col0 + wn * 64 + n * 16 + l15;
        av[n] = asrc[gcol];
        bv[n] = adst[gcol];
    }
    #pragma unroll
    for (int m = 0; m < 4; ++m) {
        #pragma unroll
        for (int r = 0; r < 4; ++r) {
            float ps = 0.f, pt = 0.f;
            #pragma unroll
            for (int n = 0; n < 4; ++n) {
                ps += acc[m][n][r] * av[n];
                pt += acc[m][n][r] * bv[n];
            }
            #pragma unroll
            for (int off = 1; off < 16; off <<= 1) {
                ps += __shfl_xor(ps, off, 64);
                pt += __shfl_xor(pt, off, 64);
            }
            int grow = row0 + wm * 64 + m * 16 + lhi * 4 + r;
            if (l15 == 0 && grow < N_NODES) {
                atomicAdd(&s_out[grow], ps);
                atomicAdd(&t_out[grow], pt);
            }
        }
    }
}

// ---------------- flash-style attention + aggregate (wave per dst) ----------------
__global__ __launch_bounds__(256) void aggregate_kernel(const unsigned short* __restrict__ hW,
                                                        const float* __restrict__ s,
                                                        const float* __restrict__ t,
                                                        const int* __restrict__ rowptr,
                                                        const int* __restrict__ ssrc,
                                                        const float* __restrict__ bias,
                                                        unsigned short* __restrict__ hout) {
    int v = (blockIdx.x * blockDim.x + threadIdx.x) >> 6;
    int lane = threadIdx.x & 63;
    if (v >= N_NODES) return;
    int beg = rowptr[v];
    int deg = rowptr[v + 1] - beg;
    float tv = t[v];
    float m = -1e30f;
    float denom = 0.f;
    float acc[8];
    #pragma unroll
    for (int j = 0; j < 8; ++j) acc[j] = 0.f;
    int half = lane >> 5;      // 0: edge i, 1: edge i+1
    int l32 = lane & 31;

    for (int base = 0; base < deg; base += 64) {
        int rem = deg - base; if (rem > 64) rem = 64;
        // lane-parallel scores for this chunk of up to 64 edges
        int u = 0; float e = -1e30f;
        if (lane < rem) {
            u = ssrc[beg + base + lane];
            float ev = s[u] + tv;
            e = (ev > 0.f) ? ev : NEG_SLOPE * ev;
        }
        float cm = e;
        #pragma unroll
        for (int off = 32; off; off >>= 1) cm = fmaxf(cm, __shfl_xor(cm, off, 64));
        float newm = fmaxf(m, cm);
        float scale = __expf(m - newm);          // 0 on first chunk
        float p = (lane < rem) ? __expf(e - newm) : 0.f;
        float ws = p;
        #pragma unroll
        for (int off = 32; off; off >>= 1) ws += __shfl_xor(ws, off, 64);
        denom = denom * scale + ws;
        m = newm;
        #pragma unroll
        for (int j = 0; j < 8; ++j) acc[j] *= scale;
        // gather rows, 2 edges per iteration (16B per lane)
        for (int i = 0; i < rem; i += 2) {
            int idx = i + half;                   // <= 63 always
            float pj = __shfl(p, idx, 64);        // 0 for out-of-range slot
            int uj = __shfl(u, idx, 64);
            short8 hv = *(const short8*)&hW[(size_t)uj * D + l32 * 8];
            #pragma unroll
            for (int j = 0; j < 8; ++j)
                acc[j] += pj * bf2f((unsigned short)hv[j]);
        }
    }
    // combine the two halves
    #pragma unroll
    for (int j = 0; j < 8; ++j) acc[j] += __shfl_xor(acc[j], 32, 64);
    float inv = 1.f / denom;
    if (half == 0) {
        float4 b0 = *(const float4*)&bias[l32 * 8];
        float4 b1 = *(const float4*)&bias[l32 * 8 + 4];
        float bb[8] = {b0.x, b0.y, b0.z, b0.w, b1.x, b1.y, b1.z, b1.w};
        short8 o;
        #pragma unroll
        for (int j = 0; j < 8; ++j) {
            float val = fmaxf(acc[j] * inv + bb[j], 0.f);
            o[j] = (short)f2bf(val);
        }
        *(short8*)&hout[(size_t)v * D + l32 * 8] = o;
    }
}

// ---------------- pooling ----------------
__global__ void growptr_kernel(const int* __restrict__ batch, int* __restrict__ growptr) {
    int n = blockIdx.x * blockDim.x + threadIdx.x;
    if (n >= N_NODES) return;
    int b = batch[n];
    int prev = (n == 0) ? -1 : batch[n - 1];
    for (int g = prev + 1; g <= b; ++g) growptr[g] = n;
    if (n == N_NODES - 1) {
        for (int g = b + 1; g <= NGRAPH; ++g) growptr[g] = N_NODES;
    }
}

__global__ __launch_bounds__(256) void pool_kernel(const unsigned short* __restrict__ h,
                                                   const int* __restrict__ growptr,
                                                   float* __restrict__ feats) {
    int g = (blockIdx.x * blockDim.x + threadIdx.x) >> 6;
    int lane = threadIdx.x & 63;
    if (g >= NGRAPH) return;
    int beg = growptr[g], end = growptr[g + 1];
    float4 add = make_float4(0.f, 0.f, 0.f, 0.f);
    float4 mx = make_float4(-1e30f, -1e30f, -1e30f, -1e30f);
    for (int v = beg; v < end; ++v) {
        ushort4 hv = *(const ushort4*)&h[(size_t)v * D + lane * 4];
        float h0 = bf2f(hv.x), h1 = bf2f(hv.y), h2 = bf2f(hv.z), h3 = bf2f(hv.w);
        add.x += h0; add.y += h1; add.z += h2; add.w += h3;
        mx.x = fmaxf(mx.x, h0); mx.y = fmaxf(mx.y, h1);
        mx.z = fmaxf(mx.z, h2); mx.w = fmaxf(mx.w, h3);
    }
    float cnt = (float)(end - beg);
    float invc = 1.f / fmaxf(cnt, 1.f);
    if (cnt <= 0.f) { mx = make_float4(0.f, 0.f, 0.f, 0.f); }
    float4 mean = make_float4(add.x * invc, add.y * invc, add.z * invc, add.w * invc);
    float* fr = feats + (size_t)g * 3 * D;
    *(float4*)&fr[0 * D + 4 * lane] = mean;
    *(float4*)&fr[1 * D + 4 * lane] = add;
    *(float4*)&fr[2 * D + 4 * lane] = mx;
}

// ---------------- final linear ----------------
__global__ __launch_bounds__(128) void final_linear(const float* __restrict__ feats,
                                                    const float* __restrict__ lw,
                                                    const float* __restrict__ lb,
                                                    float* __restrict__ out) {
    int g = blockIdx.x;
    int j = threadIdx.x;   // 0..127
    __shared__ float f[3 * D];
    for (int i = j; i < 3 * D; i += OUTD) f[i] = feats[(size_t)g * 3 * D + i];
    __syncthreads();
    float acc = lb[j];
    #pragma unroll 8
    for (int k = 0; k < 3 * D; ++k)
        acc += f[k] * lw[k * OUTD + j];
    out[g * OUTD + j] = acc;
}

extern "C" void kernel_launch(void* const* d_in, const int* in_sizes, int n_in,
                              void* d_out, int out_size, void* d_ws, size_t ws_size,
                              hipStream_t stream) {
    const int*   x        = (const int*)d_in[0];
    const int*   edge_idx = (const int*)d_in[1];
    const int*   batch    = (const int*)d_in[2];
    const float* atom_emb = (const float*)d_in[3];
    const float* Ws       = (const float*)d_in[4];
    const float* a_src    = (const float*)d_in[5];
    const float* a_dst    = (const float*)d_in[6];
    const float* biases   = (const float*)d_in[7];
    const float* lin_w    = (const float*)d_in[8];
    const float* lin_b    = (const float*)d_in[9];
    float* out = (float*)d_out;

    char* ws = (char*)d_ws;
    size_t off = 0;
    auto alloc = [&](size_t bytes) -> void* {
        void* p = ws + off;
        off += (bytes + 255) & ~(size_t)255;
        return p;
    };
    unsigned short* bufA = (unsigned short*)alloc(sizeof(short) * (size_t)N_NODES * D);
    unsigned short* bufB = (unsigned short*)alloc(sizeof(short) * (size_t)N_NODES * D);
    unsigned short* Wt   = (unsigned short*)alloc(sizeof(short) * NLAYERS * D * D);
    float* s      = (float*)alloc(sizeof(float) * N_NODES);
    float* t      = (float*)alloc(sizeof(float) * N_NODES);
    int*   deg    = (int*)alloc(sizeof(int) * N_NODES);       // reused as cursor
    int*   rowptr = (int*)alloc(sizeof(int) * (N_NODES + 1));
    int*   ssrc   = (int*)alloc(sizeof(int) * (N_EDGES + N_NODES));
    int*   growp  = (int*)alloc(sizeof(int) * (NGRAPH + 1));
    float* feats  = (float*)alloc(sizeof(float) * (size_t)NGRAPH * 3 * D);

    const int* esrc = edge_idx;
    const int* edst = edge_idx + N_EDGES;

    set_deg_one<<<(N_NODES + 255) / 256, 256, 0, stream>>>(deg);
    hist_dst<<<(N_EDGES + 255) / 256, 256, 0, stream>>>(edst, deg);
    scan_rowptr<<<1, 1024, 0, stream>>>(deg, rowptr);
    init_cursor<<<(N_NODES + 255) / 256, 256, 0, stream>>>(rowptr, deg, ssrc);
    scatter_edges<<<(N_EDGES + 255) / 256, 256, 0, stream>>>(esrc, edst, deg, ssrc);

    wt_kernel<<<NLAYERS * D * D / 256, 256, 0, stream>>>(Ws, Wt);
    atom_encoder<<<(N_NODES + 3) / 4, 256, 0, stream>>>(x, atom_emb, bufA);

    for (int l = 0; l < NLAYERS; ++l) {
        zero_st<<<(N_NODES + 255) / 256, 256, 0, stream>>>(s, t);
        dim3 ggrid((N_NODES + GBM - 1) / GBM, D / GBN);
        gemm_bf16<<<ggrid, 256, 0, stream>>>(bufA, Wt + (size_t)l * D * D,
                                             a_src + l * D, a_dst + l * D,
                                             bufB, s, t);
        aggregate_kernel<<<(N_NODES + 3) / 4, 256, 0, stream>>>(bufB, s, t, rowptr, ssrc,
                                                                biases + l * D, bufA);
    }

    growptr_kernel<<<(N_NODES + 255) / 256, 256, 0, stream>>>(batch, growp);
    pool_kernel<<<(NGRAPH + 3) / 4, 256, 0, stream>>>(bufA, growp, feats);
    final_linear<<<NGRAPH, OUTD, 0, stream>>>(feats, lin_w, lin_b, out);
}

// Round 4
// 536.188 us; speedup vs baseline: 2.3666x; 1.1473x over previous
//
#include <hip/hip_runtime.h>
#include <math.h>

#define N_NODES 50000
#define N_EDGES 800000
#define NGRAPH  1024
#define D       256
#define OUTD    128
#define NFEAT   9
#define VOCABSZ 100
#define NLAYERS 4
#define NEG_SLOPE 0.2f
#define SCAN_NBLK ((N_NODES + 255) / 256)   // 196

typedef __attribute__((ext_vector_type(8))) short short8;   // 8 bf16 (4 VGPRs)
typedef __attribute__((ext_vector_type(4))) float f32x4;

static __device__ __forceinline__ unsigned short f2bf(float f) {
    unsigned int u = __float_as_uint(f);
    u = (u + 0x7FFFu + ((u >> 16) & 1u)) >> 16;
    return (unsigned short)u;
}
static __device__ __forceinline__ float bf2f(unsigned short u) {
    return __uint_as_float(((unsigned int)u) << 16);
}

#define GLOAD_LDS16(g, l) __builtin_amdgcn_global_load_lds( \
    (const __attribute__((address_space(1))) void*)(g), \
    (__attribute__((address_space(3))) void*)(l), 16, 0, 0)

// ---------------- CSR build ----------------
__global__ void set_deg_one(int* deg) {
    int v = blockIdx.x * blockDim.x + threadIdx.x;
    if (v < N_NODES) deg[v] = 1;   // self-loop
}

__global__ void hist_dst(const int* __restrict__ dst, int* __restrict__ deg) {
    int e = blockIdx.x * blockDim.x + threadIdx.x;
    if (e < N_EDGES) atomicAdd(&deg[dst[e]], 1);
}

// hierarchical scan: (1) per-block sums, (2) scan block sums, (3) per-block rescan
__global__ __launch_bounds__(256) void block_sum(const int* __restrict__ deg, int* __restrict__ bsum) {
    int i = blockIdx.x * 256 + threadIdx.x;
    int v = (i < N_NODES) ? deg[i] : 0;
    #pragma unroll
    for (int off = 32; off; off >>= 1) v += __shfl_down(v, off, 64);
    __shared__ int ws[4];
    if ((threadIdx.x & 63) == 0) ws[threadIdx.x >> 6] = v;
    __syncthreads();
    if (threadIdx.x == 0) bsum[blockIdx.x] = ws[0] + ws[1] + ws[2] + ws[3];
}

__global__ __launch_bounds__(256) void scan_bsum(int* __restrict__ bsum, int* __restrict__ rowptr) {
    __shared__ int sh[256];
    int tid = threadIdx.x;
    int v = (tid < SCAN_NBLK) ? bsum[tid] : 0;
    sh[tid] = v;
    __syncthreads();
    for (int off = 1; off < 256; off <<= 1) {
        int u = (tid >= off) ? sh[tid - off] : 0;
        __syncthreads();
        sh[tid] += u;
        __syncthreads();
    }
    if (tid < SCAN_NBLK) bsum[tid] = (tid > 0) ? sh[tid - 1] : 0;   // exclusive offsets
    if (tid == SCAN_NBLK - 1) rowptr[N_NODES] = sh[tid];            // total
}

__global__ __launch_bounds__(256) void scan_block(const int* __restrict__ deg,
                                                  const int* __restrict__ boffs,
                                                  int* __restrict__ rowptr) {
    __shared__ int sh[256];
    int tid = threadIdx.x;
    int i = blockIdx.x * 256 + tid;
    int v = (i < N_NODES) ? deg[i] : 0;
    sh[tid] = v;
    __syncthreads();
    for (int off = 1; off < 256; off <<= 1) {
        int u = (tid >= off) ? sh[tid - off] : 0;
        __syncthreads();
        sh[tid] += u;
        __syncthreads();
    }
    if (i < N_NODES) rowptr[i] = boffs[blockIdx.x] + sh[tid] - v;   // exclusive
}

__global__ void init_cursor(const int* __restrict__ rowptr, int* __restrict__ cursor, int* __restrict__ ssrc) {
    int v = blockIdx.x * blockDim.x + threadIdx.x;
    if (v < N_NODES) {
        int p = rowptr[v];
        cursor[v] = p + 1;
        ssrc[p] = v;          // self-loop first
    }
}

__global__ void scatter_edges(const int* __restrict__ src, const int* __restrict__ dst,
                              int* __restrict__ cursor, int* __restrict__ ssrc) {
    int e = blockIdx.x * blockDim.x + threadIdx.x;
    if (e < N_EDGES) {
        int pos = atomicAdd(&cursor[dst[e]], 1);
        ssrc[pos] = src[e];
    }
}

// ---------------- W transpose + bf16 convert: Wt[l][n][k] = W[l][k][n] ----------------
__global__ __launch_bounds__(256) void wt_kernel(const float* __restrict__ W, unsigned short* __restrict__ Wt) {
    int t = blockIdx.x * 256 + threadIdx.x;           // over l*65536 + k*256 + n
    int l = t >> 16;
    int k = (t >> 8) & 255;
    int n = t & 255;
    float v = W[t];
    Wt[(l << 16) + n * 256 + k] = f2bf(v);
}

__global__ void zero_st(float* __restrict__ s, float* __restrict__ t) {
    int i = blockIdx.x * blockDim.x + threadIdx.x;
    if (i < N_NODES) { s[i] = 0.f; t[i] = 0.f; }
}

// ---------------- Atom encoder (bf16 out) ----------------
__global__ __launch_bounds__(256) void atom_encoder(const int* __restrict__ x,
                                                    const float* __restrict__ emb,
                                                    unsigned short* __restrict__ h) {
    int node = blockIdx.x * 4 + (threadIdx.x >> 6);
    int lane = threadIdx.x & 63;
    if (node >= N_NODES) return;
    float4 acc = make_float4(0.f, 0.f, 0.f, 0.f);
    #pragma unroll
    for (int f = 0; f < NFEAT; ++f) {
        int xi = x[node * NFEAT + f];
        float4 v = *(const float4*)&emb[(size_t)(f * VOCABSZ + xi) * D + lane * 4];
        acc.x += v.x; acc.y += v.y; acc.z += v.z; acc.w += v.w;
    }
    ushort4 o;
    o.x = f2bf(acc.x); o.y = f2bf(acc.y); o.z = f2bf(acc.z); o.w = f2bf(acc.w);
    *(ushort4*)&h[node * D + lane * 4] = o;
}

// ---------------- bf16 MFMA GEMM + fused s/t epilogue ----------------
#define GBM 128
#define GBN 128
#define GBK 64
__global__ __launch_bounds__(256) void gemm_bf16(const unsigned short* __restrict__ A,
                                                 const unsigned short* __restrict__ Wt,
                                                 const float* __restrict__ asrc,
                                                 const float* __restrict__ adst,
                                                 unsigned short* __restrict__ C,
                                                 float* __restrict__ s_out,
                                                 float* __restrict__ t_out) {
    __shared__ unsigned short a_s[2][GBM * GBK];
    __shared__ unsigned short b_s[2][GBM * GBK];
    int row0 = blockIdx.x * GBM;
    int col0 = blockIdx.y * GBN;
    int tid = threadIdx.x;
    int wid = tid >> 6;
    int lane = tid & 63;
    int wm = wid >> 1, wn = wid & 1;     // 2x2 wave grid, each wave 64x64
    int l15 = lane & 15;
    int lhi = lane >> 4;                 // 0..3

    int srcA[4], srcB[4];
    #pragma unroll
    for (int q = 0; q < 4; ++q) {
        int slot = (wid * 4 + q) * 64 + lane;   // 0..1023
        int r = slot >> 3, c = slot & 7;
        int ra = row0 + r; if (ra > N_NODES - 1) ra = N_NODES - 1;
        srcA[q] = ra * D + ((c ^ (r & 7)) << 3);
        srcB[q] = (col0 + r) * D + ((c ^ (r & 7)) << 3);
    }

    f32x4 acc[4][4];
    #pragma unroll
    for (int i = 0; i < 4; ++i)
        #pragma unroll
        for (int j = 0; j < 4; ++j) acc[i][j] = (f32x4){0.f, 0.f, 0.f, 0.f};

    #pragma unroll
    for (int q = 0; q < 4; ++q) {
        GLOAD_LDS16(A + srcA[q], &a_s[0][(wid * 4 + q) * 512]);
        GLOAD_LDS16(Wt + srcB[q], &b_s[0][(wid * 4 + q) * 512]);
    }
    __syncthreads();

    #pragma unroll
    for (int step = 0; step < 4; ++step) {
        int cur = step & 1;
        if (step < 3) {
            int k0 = (step + 1) * GBK;
            #pragma unroll
            for (int q = 0; q < 4; ++q) {
                GLOAD_LDS16(A + srcA[q] + k0, &a_s[cur ^ 1][(wid * 4 + q) * 512]);
                GLOAD_LDS16(Wt + srcB[q] + k0, &b_s[cur ^ 1][(wid * 4 + q) * 512]);
            }
        }
        #pragma unroll
        for (int ks = 0; ks < 2; ++ks) {
            short8 af[4], bf[4];
            #pragma unroll
            for (int m = 0; m < 4; ++m) {
                int r = wm * 64 + m * 16 + l15;
                int c = ks * 4 + lhi;
                af[m] = *(const short8*)&a_s[cur][r * GBK + ((c ^ (r & 7)) << 3)];
            }
            #pragma unroll
            for (int n = 0; n < 4; ++n) {
                int r = wn * 64 + n * 16 + l15;
                int c = ks * 4 + lhi;
                bf[n] = *(const short8*)&b_s[cur][r * GBK + ((c ^ (r & 7)) << 3)];
            }
            #pragma unroll
            for (int m = 0; m < 4; ++m)
                #pragma unroll
                for (int n = 0; n < 4; ++n)
                    acc[m][n] = __builtin_amdgcn_mfma_f32_16x16x32_bf16(af[m], bf[n], acc[m][n], 0, 0, 0);
        }
        __syncthreads();
    }

    // epilogue 1: C bf16 store. C/D layout: col=lane&15, row=(lane>>4)*4+reg
    #pragma unroll
    for (int m = 0; m < 4; ++m) {
        #pragma unroll
        for (int r = 0; r < 4; ++r) {
            int grow = row0 + wm * 64 + m * 16 + lhi * 4 + r;
            if (grow < N_NODES) {
                #pragma unroll
                for (int n = 0; n < 4; ++n) {
                    int gcol = col0 + wn * 64 + n * 16 + l15;
                    C[(size_t)grow * D + gcol] = f2bf(acc[m][n][r]);
                }
            }
        }
    }

    // epilogue 2: fused partial s,t (fp32) per row over this block's 128 cols
    float av[4], bv[4];
    #pragma unroll
    for (int n = 0; n < 4; ++n) {
        int gcol = col0 + wn * 64 + n * 16 + l15;
        av[n] = asrc[gcol];
        bv[n] = adst[gcol];
    }
    #pragma unroll
    for (int m = 0; m < 4; ++m) {
        #pragma unroll
        for (int r = 0; r < 4; ++r) {
            float ps = 0.f, pt = 0.f;
            #pragma unroll
            for (int n = 0; n < 4; ++n) {
                ps += acc[m][n][r] * av[n];
                pt += acc[m][n][r] * bv[n];
            }
            #pragma unroll
            for (int off = 1; off < 16; off <<= 1) {
                ps += __shfl_xor(ps, off, 64);
                pt += __shfl_xor(pt, off, 64);
            }
            int grow = row0 + wm * 64 + m * 16 + lhi * 4 + r;
            if (l15 == 0 && grow < N_NODES) {
                atomicAdd(&s_out[grow], ps);
                atomicAdd(&t_out[grow], pt);
            }
        }
    }
}

// ---------------- flash-style attention + aggregate (wave per dst) ----------------
__global__ __launch_bounds__(256) void aggregate_kernel(const unsigned short* __restrict__ hW,
                                                        const float* __restrict__ s,
                                                        const float* __restrict__ t,
                                                        const int* __restrict__ rowptr,
                                                        const int* __restrict__ ssrc,
                                                        const float* __restrict__ bias,
                                                        unsigned short* __restrict__ hout) {
    int v = (blockIdx.x * blockDim.x + threadIdx.x) >> 6;
    int lane = threadIdx.x & 63;
    if (v >= N_NODES) return;
    int beg = rowptr[v];
    int deg = rowptr[v + 1] - beg;
    float tv = t[v];
    float m = -1e30f;
    float denom = 0.f;
    float acc[8];
    #pragma unroll
    for (int j = 0; j < 8; ++j) acc[j] = 0.f;
    int half = lane >> 5;      // which of 2 edges in a pair
    int l32 = lane & 31;

    for (int base = 0; base < deg; base += 64) {
        int rem = deg - base; if (rem > 64) rem = 64;
        // lane-parallel scores for this chunk of up to 64 edges
        int u = 0; float e = -1e30f;
        if (lane < rem) {
            u = ssrc[beg + base + lane];
            float ev = s[u] + tv;
            e = (ev > 0.f) ? ev : NEG_SLOPE * ev;
        }
        float cm = e;
        #pragma unroll
        for (int off = 32; off; off >>= 1) cm = fmaxf(cm, __shfl_xor(cm, off, 64));
        float newm = fmaxf(m, cm);
        float scale = __expf(m - newm);          // 0 on first chunk
        float p = (lane < rem) ? __expf(e - newm) : 0.f;
        float ws = p;
        #pragma unroll
        for (int off = 32; off; off >>= 1) ws += __shfl_xor(ws, off, 64);
        denom = denom * scale + ws;
        m = newm;
        #pragma unroll
        for (int j = 0; j < 8; ++j) acc[j] *= scale;
        // gather rows, 4 edges / 2 loads per lane per iteration (MLP x2)
        for (int i = 0; i < rem; i += 4) {
            int idx0 = i + half;                  // <= 61
            int idx1 = i + 2 + half;              // <= 63
            float p0 = __shfl(p, idx0, 64);
            int   u0 = __shfl(u, idx0, 64);
            float p1 = __shfl(p, idx1, 64);
            int   u1 = __shfl(u, idx1, 64);
            short8 hv0 = *(const short8*)&hW[(size_t)u0 * D + l32 * 8];
            short8 hv1 = *(const short8*)&hW[(size_t)u1 * D + l32 * 8];
            #pragma unroll
            for (int j = 0; j < 8; ++j)
                acc[j] += p0 * bf2f((unsigned short)hv0[j]);
            #pragma unroll
            for (int j = 0; j < 8; ++j)
                acc[j] += p1 * bf2f((unsigned short)hv1[j]);
        }
    }
    // combine the two halves
    #pragma unroll
    for (int j = 0; j < 8; ++j) acc[j] += __shfl_xor(acc[j], 32, 64);
    float inv = 1.f / denom;
    if (half == 0) {
        float4 b0 = *(const float4*)&bias[l32 * 8];
        float4 b1 = *(const float4*)&bias[l32 * 8 + 4];
        float bb[8] = {b0.x, b0.y, b0.z, b0.w, b1.x, b1.y, b1.z, b1.w};
        short8 o;
        #pragma unroll
        for (int j = 0; j < 8; ++j) {
            float val = fmaxf(acc[j] * inv + bb[j], 0.f);
            o[j] = (short)f2bf(val);
        }
        *(short8*)&hout[(size_t)v * D + l32 * 8] = o;
    }
}

// ---------------- pooling ----------------
__global__ void growptr_kernel(const int* __restrict__ batch, int* __restrict__ growptr) {
    int n = blockIdx.x * blockDim.x + threadIdx.x;
    if (n >= N_NODES) return;
    int b = batch[n];
    int prev = (n == 0) ? -1 : batch[n - 1];
    for (int g = prev + 1; g <= b; ++g) growptr[g] = n;
    if (n == N_NODES - 1) {
        for (int g = b + 1; g <= NGRAPH; ++g) growptr[g] = N_NODES;
    }
}

__global__ __launch_bounds__(256) void pool_kernel(const unsigned short* __restrict__ h,
                                                   const int* __restrict__ growptr,
                                                   float* __restrict__ feats) {
    int g = (blockIdx.x * blockDim.x + threadIdx.x) >> 6;
    int lane = threadIdx.x & 63;
    if (g >= NGRAPH) return;
    int beg = growptr[g], end = growptr[g + 1];
    float4 add = make_float4(0.f, 0.f, 0.f, 0.f);
    float4 mx = make_float4(-1e30f, -1e30f, -1e30f, -1e30f);
    for (int v = beg; v < end; ++v) {
        ushort4 hv = *(const ushort4*)&h[(size_t)v * D + lane * 4];
        float h0 = bf2f(hv.x), h1 = bf2f(hv.y), h2 = bf2f(hv.z), h3 = bf2f(hv.w);
        add.x += h0; add.y += h1; add.z += h2; add.w += h3;
        mx.x = fmaxf(mx.x, h0); mx.y = fmaxf(mx.y, h1);
        mx.z = fmaxf(mx.z, h2); mx.w = fmaxf(mx.w, h3);
    }
    float cnt = (float)(end - beg);
    float invc = 1.f / fmaxf(cnt, 1.f);
    if (cnt <= 0.f) { mx = make_float4(0.f, 0.f, 0.f, 0.f); }
    float4 mean = make_float4(add.x * invc, add.y * invc, add.z * invc, add.w * invc);
    float* fr = feats + (size_t)g * 3 * D;
    *(float4*)&fr[0 * D + 4 * lane] = mean;
    *(float4*)&fr[1 * D + 4 * lane] = add;
    *(float4*)&fr[2 * D + 4 * lane] = mx;
}

// ---------------- final linear ----------------
__global__ __launch_bounds__(128) void final_linear(const float* __restrict__ feats,
                                                    const float* __restrict__ lw,
                                                    const float* __restrict__ lb,
                                                    float* __restrict__ out) {
    int g = blockIdx.x;
    int j = threadIdx.x;   // 0..127
    __shared__ float f[3 * D];
    for (int i = j; i < 3 * D; i += OUTD) f[i] = feats[(size_t)g * 3 * D + i];
    __syncthreads();
    float acc = lb[j];
    #pragma unroll 8
    for (int k = 0; k < 3 * D; ++k)
        acc += f[k] * lw[k * OUTD + j];
    out[g * OUTD + j] = acc;
}

extern "C" void kernel_launch(void* const* d_in, const int* in_sizes, int n_in,
                              void* d_out, int out_size, void* d_ws, size_t ws_size,
                              hipStream_t stream) {
    const int*   x        = (const int*)d_in[0];
    const int*   edge_idx = (const int*)d_in[1];
    const int*   batch    = (const int*)d_in[2];
    const float* atom_emb = (const float*)d_in[3];
    const float* Ws       = (const float*)d_in[4];
    const float* a_src    = (const float*)d_in[5];
    const float* a_dst    = (const float*)d_in[6];
    const float* biases   = (const float*)d_in[7];
    const float* lin_w    = (const float*)d_in[8];
    const float* lin_b    = (const float*)d_in[9];
    float* out = (float*)d_out;

    char* ws = (char*)d_ws;
    size_t off = 0;
    auto alloc = [&](size_t bytes) -> void* {
        void* p = ws + off;
        off += (bytes + 255) & ~(size_t)255;
        return p;
    };
    unsigned short* bufA = (unsigned short*)alloc(sizeof(short) * (size_t)N_NODES * D);
    unsigned short* bufB = (unsigned short*)alloc(sizeof(short) * (size_t)N_NODES * D);
    unsigned short* Wt   = (unsigned short*)alloc(sizeof(short) * NLAYERS * D * D);
    float* s      = (float*)alloc(sizeof(float) * N_NODES);
    float* t      = (float*)alloc(sizeof(float) * N_NODES);
    int*   deg    = (int*)alloc(sizeof(int) * N_NODES);       // reused as cursor
    int*   rowptr = (int*)alloc(sizeof(int) * (N_NODES + 1));
    int*   bsum   = (int*)alloc(sizeof(int) * 256);
    int*   ssrc   = (int*)alloc(sizeof(int) * (N_EDGES + N_NODES));
    int*   growp  = (int*)alloc(sizeof(int) * (NGRAPH + 1));
    float* feats  = (float*)alloc(sizeof(float) * (size_t)NGRAPH * 3 * D);

    const int* esrc = edge_idx;
    const int* edst = edge_idx + N_EDGES;

    set_deg_one<<<(N_NODES + 255) / 256, 256, 0, stream>>>(deg);
    hist_dst<<<(N_EDGES + 255) / 256, 256, 0, stream>>>(edst, deg);
    block_sum<<<SCAN_NBLK, 256, 0, stream>>>(deg, bsum);
    scan_bsum<<<1, 256, 0, stream>>>(bsum, rowptr);
    scan_block<<<SCAN_NBLK, 256, 0, stream>>>(deg, bsum, rowptr);
    init_cursor<<<(N_NODES + 255) / 256, 256, 0, stream>>>(rowptr, deg, ssrc);
    scatter_edges<<<(N_EDGES + 255) / 256, 256, 0, stream>>>(esrc, edst, deg, ssrc);

    wt_kernel<<<NLAYERS * D * D / 256, 256, 0, stream>>>(Ws, Wt);
    atom_encoder<<<(N_NODES + 3) / 4, 256, 0, stream>>>(x, atom_emb, bufA);

    for (int l = 0; l < NLAYERS; ++l) {
        zero_st<<<(N_NODES + 255) / 256, 256, 0, stream>>>(s, t);
        dim3 ggrid((N_NODES + GBM - 1) / GBM, D / GBN);
        gemm_bf16<<<ggrid, 256, 0, stream>>>(bufA, Wt + (size_t)l * D * D,
                                             a_src + l * D, a_dst + l * D,
                                             bufB, s, t);
        aggregate_kernel<<<(N_NODES + 3) / 4, 256, 0, stream>>>(bufB, s, t, rowptr, ssrc,
                                                                biases + l * D, bufA);
    }

    growptr_kernel<<<(N_NODES + 255) / 256, 256, 0, stream>>>(batch, growp);
    pool_kernel<<<(NGRAPH + 3) / 4, 256, 0, stream>>>(bufA, growp, feats);
    final_linear<<<NGRAPH, OUTD, 0, stream>>>(feats, lin_w, lin_b, out);
}